// Round 8
// baseline (326.363 us; speedup 1.0000x reference)
//
#include <hip/hip_runtime.h>
#include <hip/hip_bf16.h>
#include <cstdint>

#define HW 65536

typedef __attribute__((ext_vector_type(8))) short bf16x8;   // 8 bf16 = 4 VGPRs
typedef __attribute__((ext_vector_type(4))) float f32x4;

// ---- flag slots (uint index, each slot stride 4 uints = 16 B) ----
#define D0   0        // [1024] P0 done (per block: both tile stats written)
#define D1A  4096     // [128]  P1a done (per stats-reduce block)
#define D2   4624     // [1024] P2 done (pool rows)
#define D3   8720     // [1024] P3 done (conv tile stats)
#define FLAGS_BYTES 51264   // 12816 uints
// ---- float offsets ----
#define OFF_PARTS 12816     // [8][64][256] per-tile row sums
#define OFF_PARTM 143888    // [8][64][256] per-tile row maxes
#define OFF_AVG   274960    // [8][64] channel means
#define OFF_MXA   275472    // [8][64] channel maxes
#define OFF_POOL  292368    // u32 [8][HW] packed bf16 (mean, max)
#define OFF_BM    1340944   // [1024] per-conv-tile y max
#define OFF_BS    1341968   // [1024] per-conv-tile sumexp
#define OFF_Y     1342992   // [8][HW]

// write-through (agent-visible) stores -- no cache-maintenance instructions
__device__ __forceinline__ void st_wt_f32(float* p, float v) {
  __hip_atomic_store(p, v, __ATOMIC_RELAXED, __HIP_MEMORY_SCOPE_AGENT);
}
__device__ __forceinline__ void st_wt_u32(unsigned* p, unsigned v) {
  __hip_atomic_store(p, v, __ATOMIC_RELAXED, __HIP_MEMORY_SCOPE_AGENT);
}

// block signals "my phase output is globally visible"
__device__ __forceinline__ void signal(unsigned* slot) {
  __syncthreads();                 // compiler drains vmcnt for all waves at barrier
  if (threadIdx.x == 0) {
    asm volatile("s_waitcnt vmcnt(0)" ::: "memory");
    st_wt_u32(slot, 1u);
  }
}

// block-wide wait: thread watches flag[idx] if active; RELAXED polls (no inv)
__device__ __forceinline__ void wait_slots(const unsigned* fl, int idx, bool active) {
  bool ok;
  do {
    ok = true;
    if (active)
      ok = (__hip_atomic_load(fl + idx, __ATOMIC_RELAXED, __HIP_MEMORY_SCOPE_AGENT) != 0u);
    if (!ok) __builtin_amdgcn_s_sleep(4);
  } while (__syncthreads_and((int)ok) == 0);
  asm volatile("" ::: "memory");
}

// stage one 64x256 f32 tile -> LDS bf16 [64][258] (cvt_pk path, coalesced 1KB/inst)
__device__ __forceinline__ void stage_tile(const float* __restrict__ fb, int n0,
                                           unsigned short* tile, int tid) {
  int r0 = tid >> 6, cb = (tid & 63) << 2;
#pragma unroll 4
  for (int i = 0; i < 16; ++i) {
    int row = (i << 2) + r0;
    float4 v = *(const float4*)(fb + (size_t)row * HW + n0 + cb);
    __hip_bfloat162 lo = __float22bfloat162_rn(make_float2(v.x, v.y));
    __hip_bfloat162 hi = __float22bfloat162_rn(make_float2(v.z, v.w));
    unsigned* d = (unsigned*)(tile + row * 258 + cb);
    d[0] = *(unsigned*)&lo;
    d[1] = *(unsigned*)&hi;
  }
}

// P0 tile pass: per-row sum/max partials; STORE=true also converts into LDS
template <bool STORE>
__device__ __forceinline__ void p0_tile(const float* __restrict__ fb, int n0, int ssp,
                                        int chunk, unsigned short* tile,
                                        float* __restrict__ ws, int lane, int wv) {
  int ls = lane >> 4, lp = lane & 15;
#pragma unroll
  for (int rg = 0; rg < 4; ++rg) {
    int row = (wv << 4) + (rg << 2) + ls;
    const float4* rp = (const float4*)(fb + (size_t)row * HW + n0);
    float sum = 0.f, mx = -3.4e38f;
#pragma unroll
    for (int i = 0; i < 4; ++i) {
      int j = lp + (i << 4);
      float4 v = rp[j];
      sum += (v.x + v.y) + (v.z + v.w);
      mx = fmaxf(mx, fmaxf(fmaxf(v.x, v.y), fmaxf(v.z, v.w)));
      if (STORE) {
        __hip_bfloat162 lo = __float22bfloat162_rn(make_float2(v.x, v.y));
        __hip_bfloat162 hi = __float22bfloat162_rn(make_float2(v.z, v.w));
        unsigned* d = (unsigned*)(tile + row * 258 + (j << 2));
        d[0] = *(unsigned*)&lo;
        d[1] = *(unsigned*)&hi;
      }
    }
#pragma unroll
    for (int o = 1; o < 16; o <<= 1) {
      sum += __shfl_xor(sum, o);
      mx = fmaxf(mx, __shfl_xor(mx, o));
    }
    if (lp == 0) {
      st_wt_f32(ws + OFF_PARTS + (((ssp << 6) + row) << 8) + chunk, sum);
      st_wt_f32(ws + OFF_PARTM + (((ssp << 6) + row) << 8) + chunk, mx);
    }
  }
}

// ---------------- persistent mega-kernel ----------------
// grid MUST be 1024 x 256. LDS ~36KB + launch_bounds(256,4) => 4 blocks/CU => co-resident.
__global__ __launch_bounds__(256, 4) void k_mega(
    const float* __restrict__ f1, const float* __restrict__ f2,
    float* __restrict__ ws, float* __restrict__ out,
    const float* __restrict__ w_avg1, const float* __restrict__ b_avg1,
    const float* __restrict__ w_max1, const float* __restrict__ b_max1,
    const float* __restrict__ w_avg11, const float* __restrict__ b_avg11,
    const float* __restrict__ w_max11, const float* __restrict__ b_max11,
    const float* __restrict__ w_avg2, const float* __restrict__ b_avg2,
    const float* __restrict__ w_max2, const float* __restrict__ b_max2,
    const float* __restrict__ w_avg22, const float* __restrict__ b_avg22,
    const float* __restrict__ w_max22, const float* __restrict__ b_max22,
    const float* __restrict__ cw1, const float* __restrict__ cb1,
    const float* __restrict__ cw2, const float* __restrict__ cb2) {

  __shared__ union {
    unsigned short tile[64 * 258];                               // 33024 B
    struct { float pl[2][20][36]; float t1l[18][34]; } cv;       // conv phase
    float yst[512];                                              // final phase
  } sm;
  __shared__ float red[8];
  // MLP/P scratch -- separate from tile (tile stays resident across P1)
  __shared__ float s_in[4][64];        // avg1, mx1, avg2, mx2
  __shared__ float s_h[4][32];         // ha1, hm1, ha2, hm2
  __shared__ float s_a1[64], s_a2[64], s_mm[4];
  __shared__ float s_rm[2][64], s_ri[2][64];   // per-row softmax max & 1/sum

  unsigned* fl = (unsigned*)ws;
  const int tid = threadIdx.x;
  const int bx  = blockIdx.x;
  const int lane = tid & 63, wv = tid >> 6;

  const int ss1 = bx >> 8, chunk = bx & 255, n0 = chunk << 8;
  const float* fb1 = f1 + ((size_t)ss1 << 22);   // slice ss1   (f1 batch ss1)
  const float* fb2 = f2 + ((size_t)ss1 << 22);   // slice ss1+4 (f2 batch ss1)

  // ======== P0: tile1 -> LDS bf16 + stats; tile2 stats-only ========
  p0_tile<true >(fb1, n0, ss1,     chunk, sm.tile, ws, lane, wv);
  p0_tile<false>(fb2, n0, ss1 + 4, chunk, sm.tile, ws, lane, wv);
  signal(fl + D0 + (bx << 2));

  // ======== P1a: stats reduction over 256 tiles (blocks 0..127, 4 rows each) ========
  if (bx < 128) {
    int ssx = bx >> 4;   // slice of my rows
    wait_slots(fl, D0 + ((((ssx & 3) << 8) | tid) << 2), true);
    int r = (bx << 2) + wv;                       // global row = ss*64+ch
    float4 s4 = *(const float4*)(ws + OFF_PARTS + (r << 8) + (lane << 2));
    float4 m4 = *(const float4*)(ws + OFF_PARTM + (r << 8) + (lane << 2));
    float s = (s4.x + s4.y) + (s4.z + s4.w);
    float m = fmaxf(fmaxf(m4.x, m4.y), fmaxf(m4.z, m4.w));
    for (int o = 32; o > 0; o >>= 1) {
      s += __shfl_xor(s, o);
      m = fmaxf(m, __shfl_xor(m, o));
    }
    if (lane == 0) {
      st_wt_f32(ws + OFF_AVG + r, s * (1.f / 65536.f));
      st_wt_f32(ws + OFF_MXA + r, m);
    }
    signal(fl + D1A + (bx << 2));
  }

  // ======== P1b (distributed): every block redundantly computes MLP + P stats ========
  {
    int fidx = (tid < 16) ? (ss1 * 16 + tid) : ((ss1 + 4) * 16 + (tid - 16));
    wait_slots(fl, D1A + (fidx << 2), tid < 32);
  }
  if (tid < 64) {
    s_in[0][tid] = ws[OFF_AVG + (ss1 << 6) + tid];
    s_in[1][tid] = ws[OFF_MXA + (ss1 << 6) + tid];
    s_in[2][tid] = ws[OFF_AVG + ((ss1 + 4) << 6) + tid];
    s_in[3][tid] = ws[OFF_MXA + ((ss1 + 4) << 6) + tid];
  }
  __syncthreads();
  if (tid < 128) {                    // layer 1: 4 x 32 hidden units
    int u = tid & 31, which = tid >> 5;
    const float* W = (which == 0) ? w_avg1 : (which == 1) ? w_max1
                   : (which == 2) ? w_avg2 : w_max2;
    const float* B = (which == 0) ? b_avg1 : (which == 1) ? b_max1
                   : (which == 2) ? b_avg2 : b_max2;
    float s = B[u];
    for (int c2 = 0; c2 < 64; ++c2) s += W[u * 64 + c2] * s_in[which][c2];
    s_h[which][u] = fmaxf(s, 0.f);
  }
  __syncthreads();
  if (tid < 128) {                    // layer 2: a1[64], a2[64]
    int u = tid & 63, which = tid >> 6;
    const float* Wa = which ? w_avg22 : w_avg11;
    const float* Wm = which ? w_max22 : w_max11;
    float s = which ? (b_avg22[u] + b_max22[u]) : (b_avg11[u] + b_max11[u]);
    const float* ha = s_h[which ? 2 : 0];
    const float* hm = s_h[which ? 3 : 1];
    for (int k = 0; k < 32; ++k) s += Wa[u * 32 + k] * ha[k] + Wm[u * 32 + k] * hm[k];
    (which ? s_a2 : s_a1)[u] = s;
  }
  __syncthreads();
  if (wv == 0) {                      // extrema of a2
    float v = s_a2[lane], mxv = v, mnv = v;
    for (int o = 32; o > 0; o >>= 1) {
      mxv = fmaxf(mxv, __shfl_xor(mxv, o));
      mnv = fminf(mnv, __shfl_xor(mnv, o));
    }
    if (lane == 0) { s_mm[0] = mxv; s_mm[1] = mnv; }
  } else if (wv == 1) {               // extrema of a1
    float v = s_a1[lane], mxv = v, mnv = v;
    for (int o = 32; o > 0; o >>= 1) {
      mxv = fmaxf(mxv, __shfl_xor(mxv, o));
      mnv = fminf(mnv, __shfl_xor(mnv, o));
    }
    if (lane == 0) { s_mm[2] = mxv; s_mm[3] = mnv; }
  }
  __syncthreads();
  {                                    // per-row softmax stats: 128 rows x 2 threads
    int r = tid >> 1, half = tid & 1;
    int sel = r >> 6, i = r & 63;
    float sv = sel ? s_a2[i] : s_a1[i];
    const float* col = sel ? s_a1 : s_a2;
    float mrow = (sv >= 0.f) ? sv * (sel ? s_mm[2] : s_mm[0])
                             : sv * (sel ? s_mm[3] : s_mm[1]);
    float sum = 0.f;
    int j0 = half << 5;
    for (int j = j0; j < j0 + 32; ++j) sum += __expf(sv * col[j] - mrow);
    sum += __shfl_xor(sum, 1);        // tid pairs (2r, 2r+1) share a wave
    if (half == 0) { s_rm[sel][i] = mrow; s_ri[sel][i] = 1.f / sum; }
  }
  __syncthreads();

  // ======== P2: at = P @ f via MFMA, channel mean/max -> packed pool ========
  {
    const int c = lane & 15, q = lane >> 4;
    const int pxb = wv << 6;

    auto build_A = [&](int sel, bf16x8 (&A)[4][2]) {
      const float* col = sel ? s_a1 : s_a2;
#pragma unroll
      for (int mt = 0; mt < 4; ++mt) {
        int i = mt * 16 + c;
        float sv = sel ? s_a2[i] : s_a1[i];
        float mrow = s_rm[sel][i], inv = s_ri[sel][i];
#pragma unroll
        for (int s = 0; s < 2; ++s) {
          union { bf16x8 v; __hip_bfloat162 h[4]; } u;
#pragma unroll
          for (int jj = 0; jj < 4; ++jj) {
            int j = s * 32 + q * 8 + jj * 2;
            float e0 = __expf(sv * col[j]     - mrow) * inv;
            float e1 = __expf(sv * col[j + 1] - mrow) * inv;
            u.h[jj] = __float22bfloat162_rn(make_float2(e0, e1));
          }
          A[mt][s] = u.v;
        }
      }
    };

    auto mfma_tile = [&](int ss, const bf16x8 (&A)[4][2]) {
      unsigned* poolu = (unsigned*)(ws + OFF_POOL) + (size_t)ss * HW;
#pragma unroll
      for (int nt = 0; nt < 4; ++nt) {
        int pcol = pxb + (nt << 4) + c;
        union { bf16x8 v; unsigned short s[8]; } u0, u1;
#pragma unroll
        for (int j = 0; j < 8; ++j) {
          u0.s[j] = sm.tile[(q * 8 + j) * 258 + pcol];
          u1.s[j] = sm.tile[(32 + q * 8 + j) * 258 + pcol];
        }
        f32x4 acc[4];
#pragma unroll
        for (int mt = 0; mt < 4; ++mt) {
          acc[mt] = (f32x4){0.f, 0.f, 0.f, 0.f};
          acc[mt] = __builtin_amdgcn_mfma_f32_16x16x32_bf16(A[mt][0], u0.v, acc[mt], 0, 0, 0);
          acc[mt] = __builtin_amdgcn_mfma_f32_16x16x32_bf16(A[mt][1], u1.v, acc[mt], 0, 0, 0);
        }
        float sum = 0.f, mxv = -3.4e38f;
#pragma unroll
        for (int mt = 0; mt < 4; ++mt)
#pragma unroll
          for (int r = 0; r < 4; ++r) {
            float v = acc[mt][r];
            sum += v;
            mxv = fmaxf(mxv, v);
          }
        sum += __shfl_xor(sum, 16);
        sum += __shfl_xor(sum, 32);
        mxv = fmaxf(mxv, __shfl_xor(mxv, 16));
        mxv = fmaxf(mxv, __shfl_xor(mxv, 32));
        // pack (mean, max) as bf16x2, one u32 store per pixel
        __hip_bfloat162 pk = __float22bfloat162_rn(make_float2(sum * (1.f / 64.f), mxv));
        if (q == 0) st_wt_u32(poolu + n0 + pcol, *(unsigned*)&pk);
      }
    };

    bf16x8 A[4][2];
    build_A(0, A);
    mfma_tile(ss1, A);                 // tile 1: resident since P0
    __syncthreads();
    stage_tile(fb2, n0, sm.tile, tid); // tile 2: f2 slice, L3-hot from P0
    __syncthreads();
    build_A(1, A);
    mfma_tile(ss1 + 4, A);
  }
  signal(fl + D2 + (bx << 2));

  // ======== P3: fused conv1(relu)+conv2 on 16x32 tiles + tile softmax stats ========
  {
    int ss = bx >> 7, tile_id = bx & 127;
    int h0 = (tile_id >> 3) << 4;
    int w0 = (tile_id & 7) << 5;
    {  // wait for the <=20 pool-row producers of this halo
      int rr = h0 - 2 + tid;
      bool act = (tid < 20) && (rr >= 0) && (rr < 256);
      wait_slots(fl, D2 + ((((ss & 3) << 8) + rr) << 2), act);
    }
    const unsigned* pp = (const unsigned*)(ws + OFF_POOL) + (size_t)ss * HW;
    float c1b = cb1[0], c2b = cb2[0];
    for (int i = tid; i < 720; i += 256) {        // 20 x 36 halo pool tile (packed)
      int rr = i / 36, cc = i - rr * 36;
      int h = h0 - 2 + rr, w = w0 - 2 + cc;
      unsigned pk = 0u;
      if (h >= 0 && h < 256 && w >= 0 && w < 256) pk = pp[(h << 8) + w];
      sm.cv.pl[0][rr][cc] = __uint_as_float(pk << 16);           // mean (bf16 lo)
      sm.cv.pl[1][rr][cc] = __uint_as_float(pk & 0xffff0000u);   // max  (bf16 hi)
    }
    __syncthreads();
    for (int i = tid; i < 612; i += 256) {        // 18 x 34 t1 tile
      int rr = i / 34, cc = i - rr * 34;
      int h = h0 - 1 + rr, w = w0 - 1 + cc;
      float s = c1b;
#pragma unroll
      for (int ci = 0; ci < 2; ++ci)
#pragma unroll
        for (int kh = 0; kh < 3; ++kh)
#pragma unroll
          for (int kw = 0; kw < 3; ++kw)
            s += sm.cv.pl[ci][rr + kh][cc + kw] * cw1[ci * 9 + kh * 3 + kw];
      bool in = (h >= 0 && h < 256 && w >= 0 && w < 256);
      sm.cv.t1l[rr][cc] = in ? fmaxf(s, 0.f) : 0.f;
    }
    __syncthreads();
    float myy[2];
    float m = -3.4e38f;
#pragma unroll
    for (int k2 = 0; k2 < 2; ++k2) {              // 16 x 32 y tile, 2 px/thread
      int i = tid + (k2 << 8);
      int rr = i >> 5, cc = i & 31;
      float s = c2b;
#pragma unroll
      for (int kh = 0; kh < 3; ++kh)
#pragma unroll
        for (int kw = 0; kw < 3; ++kw)
          s += sm.cv.t1l[rr + kh][cc + kw] * cw2[kh * 3 + kw];
      st_wt_f32(ws + OFF_Y + (ss << 16) + ((h0 + rr) << 8) + w0 + cc, s);
      myy[k2] = s;
      m = fmaxf(m, s);
    }
    for (int o = 32; o > 0; o >>= 1) m = fmaxf(m, __shfl_xor(m, o));
    if (lane == 0) red[wv] = m;
    __syncthreads();
    float Mb = fmaxf(fmaxf(red[0], red[1]), fmaxf(red[2], red[3]));
    float z = __expf(myy[0] - Mb) + __expf(myy[1] - Mb);
    for (int o = 32; o > 0; o >>= 1) z += __shfl_xor(z, o);
    if (lane == 0) red[4 + wv] = z;
    __syncthreads();
    if (tid == 0) {
      st_wt_f32(ws + OFF_BM + bx, Mb);
      st_wt_f32(ws + OFF_BS + bx, red[4] + red[5] + red[6] + red[7]);
    }
  }
  signal(fl + D3 + (bx << 2));

  // ======== P4: per-slice stat combine (redundant) + o = f * (1 + g) ========
  {
    int ss = bx >> 7, wq = bx & 127;
    wait_slots(fl, D3 + ((ss * 128 + (tid & 127)) << 2), tid < 128);
    float m = (tid < 128) ? ws[OFF_BM + ss * 128 + tid] : -3.4e38f;
    for (int o = 32; o > 0; o >>= 1) m = fmaxf(m, __shfl_xor(m, o));
    if (lane == 0) red[wv] = m;
    __syncthreads();
    float M = fmaxf(fmaxf(red[0], red[1]), fmaxf(red[2], red[3]));
    float z = (tid < 128) ? __expf(ws[OFF_BM + ss * 128 + tid] - M) * ws[OFF_BS + ss * 128 + tid] : 0.f;
    for (int o = 32; o > 0; o >>= 1) z += __shfl_xor(z, o);
    if (lane == 0) red[4 + wv] = z;
    __syncthreads();
    float iZ = 1.f / (red[4] + red[5] + red[6] + red[7]);
    int p0 = wq << 9;                       // this block's 512-px span
    if (tid < 128) {
      float4 vy = *(const float4*)(ws + OFF_Y + (ss << 16) + p0 + (tid << 2));
      *(float4*)(&sm.yst[tid << 2]) = vy;
    }
    __syncthreads();
    const float* fsl = (ss >= 4) ? (f2 + ((size_t)(ss - 4) << 22))
                                 : (f1 + ((size_t)ss << 22));
    float* osl = out + ((size_t)ss << 22);
    int c0 = tid >> 7;
    int pxo = (tid & 127) << 2;
    float4 yv = *(const float4*)(&sm.yst[pxo]);
    f32x4 g;
    g.x = 1.f + __expf(yv.x - M) * iZ;
    g.y = 1.f + __expf(yv.y - M) * iZ;
    g.z = 1.f + __expf(yv.z - M) * iZ;
    g.w = 1.f + __expf(yv.w - M) * iZ;
#pragma unroll 8
    for (int i = 0; i < 32; ++i) {
      int ch = (i << 1) + c0;
      size_t gi = (size_t)ch * HW + p0 + pxo;
      f32x4 fv = *(const f32x4*)(fsl + gi);
      f32x4 o = fv * g;
      __builtin_nontemporal_store(o, (f32x4*)(osl + gi));
    }
  }
}

extern "C" void kernel_launch(void* const* d_in, const int* in_sizes, int n_in,
                              void* d_out, int out_size, void* d_ws, size_t ws_size,
                              hipStream_t stream) {
  const float* f1 = (const float*)d_in[0];
  const float* f2 = (const float*)d_in[1];
  const float* w_avg1  = (const float*)d_in[2];
  const float* b_avg1  = (const float*)d_in[3];
  const float* w_max1  = (const float*)d_in[4];
  const float* b_max1  = (const float*)d_in[5];
  const float* w_avg11 = (const float*)d_in[6];
  const float* b_avg11 = (const float*)d_in[7];
  const float* w_max11 = (const float*)d_in[8];
  const float* b_max11 = (const float*)d_in[9];
  const float* w_avg2  = (const float*)d_in[10];
  const float* b_avg2  = (const float*)d_in[11];
  const float* w_max2  = (const float*)d_in[12];
  const float* b_max2  = (const float*)d_in[13];
  const float* w_avg22 = (const float*)d_in[14];
  const float* b_avg22 = (const float*)d_in[15];
  const float* w_max22 = (const float*)d_in[16];
  const float* b_max22 = (const float*)d_in[17];
  const float* conv1_w = (const float*)d_in[18];
  const float* conv1_b = (const float*)d_in[19];
  const float* conv2_w = (const float*)d_in[20];
  const float* conv2_b = (const float*)d_in[21];
  float* ws = (float*)d_ws;
  float* out = (float*)d_out;

  // zero the flag arrays
  (void)hipMemsetAsync(d_ws, 0, FLAGS_BYTES, stream);
  k_mega<<<1024, 256, 0, stream>>>(f1, f2, ws, out,
                                   w_avg1, b_avg1, w_max1, b_max1,
                                   w_avg11, b_avg11, w_max11, b_max11,
                                   w_avg2, b_avg2, w_max2, b_max2,
                                   w_avg22, b_avg22, w_max22, b_max22,
                                   conv1_w, conv1_b, conv2_w, conv2_b);
}

// Round 9
// 319.883 us; speedup vs baseline: 1.0203x; 1.0203x over previous
//
#include <hip/hip_runtime.h>
#include <hip/hip_bf16.h>
#include <cstdint>

#define HW 65536

typedef __attribute__((ext_vector_type(8))) short bf16x8;   // 8 bf16 = 4 VGPRs
typedef __attribute__((ext_vector_type(4))) float f32x4;

// ---- flag slots (uint index, each slot stride 4 uints = 16 B) ----
#define D0   0        // [1024] P0 done (per block: both tile stats written)
#define D1A  4096     // [128]  P1a done (per stats-reduce block)
#define D2   4624     // [1024] P2 done (pool rows)
#define D3   8720     // [1024] P3 done (conv tile stats)
#define FLAGS_BYTES 51264   // 12816 uints
// ---- float offsets ----
#define OFF_PARTS 12816     // [8][64][256] per-tile row sums
#define OFF_PARTM 143888    // [8][64][256] per-tile row maxes
#define OFF_AVG   274960    // [8][64] channel means
#define OFF_MXA   275472    // [8][64] channel maxes
#define OFF_POOL  292368    // u32 [8][HW] packed bf16 (mean, max)
#define OFF_BM    1340944   // [1024] per-conv-tile y max
#define OFF_BS    1341968   // [1024] per-conv-tile sumexp
#define OFF_Y     1342992   // [8][HW]

// write-through (agent-visible) stores -- no cache-maintenance instructions
__device__ __forceinline__ void st_wt_f32(float* p, float v) {
  __hip_atomic_store(p, v, __ATOMIC_RELAXED, __HIP_MEMORY_SCOPE_AGENT);
}
__device__ __forceinline__ void st_wt_u32(unsigned* p, unsigned v) {
  __hip_atomic_store(p, v, __ATOMIC_RELAXED, __HIP_MEMORY_SCOPE_AGENT);
}

// block signals "my phase output is globally visible"
__device__ __forceinline__ void signal(unsigned* slot) {
  __syncthreads();                 // compiler drains vmcnt for all waves at barrier
  if (threadIdx.x == 0) {
    asm volatile("s_waitcnt vmcnt(0)" ::: "memory");
    st_wt_u32(slot, 1u);
  }
}

// block-wide wait: thread watches flag[idx] if active; RELAXED polls (no inv)
__device__ __forceinline__ void wait_slots(const unsigned* fl, int idx, bool active) {
  bool ok;
  do {
    ok = true;
    if (active)
      ok = (__hip_atomic_load(fl + idx, __ATOMIC_RELAXED, __HIP_MEMORY_SCOPE_AGENT) != 0u);
    if (!ok) __builtin_amdgcn_s_sleep(2);
  } while (__syncthreads_and((int)ok) == 0);
  asm volatile("" ::: "memory");
}

// stage one 64x256 f32 tile -> LDS bf16 [64][258] (cvt_pk path, coalesced 1KB/inst)
__device__ __forceinline__ void stage_tile(const float* __restrict__ fb, int n0,
                                           unsigned short* tile, int tid) {
  int r0 = tid >> 6, cb = (tid & 63) << 2;
#pragma unroll 4
  for (int i = 0; i < 16; ++i) {
    int row = (i << 2) + r0;
    float4 v = *(const float4*)(fb + (size_t)row * HW + n0 + cb);
    __hip_bfloat162 lo = __float22bfloat162_rn(make_float2(v.x, v.y));
    __hip_bfloat162 hi = __float22bfloat162_rn(make_float2(v.z, v.w));
    unsigned* d = (unsigned*)(tile + row * 258 + cb);
    d[0] = *(unsigned*)&lo;
    d[1] = *(unsigned*)&hi;
  }
}

// P0 tile pass: per-row sum/max partials; STORE=true also converts into LDS
template <bool STORE>
__device__ __forceinline__ void p0_tile(const float* __restrict__ fb, int n0, int ssp,
                                        int chunk, unsigned short* tile,
                                        float* __restrict__ ws, int lane, int wv) {
  int ls = lane >> 4, lp = lane & 15;
#pragma unroll
  for (int rg = 0; rg < 4; ++rg) {
    int row = (wv << 4) + (rg << 2) + ls;
    const float4* rp = (const float4*)(fb + (size_t)row * HW + n0);
    float sum = 0.f, mx = -3.4e38f;
#pragma unroll
    for (int i = 0; i < 4; ++i) {
      int j = lp + (i << 4);
      float4 v = rp[j];
      sum += (v.x + v.y) + (v.z + v.w);
      mx = fmaxf(mx, fmaxf(fmaxf(v.x, v.y), fmaxf(v.z, v.w)));
      if (STORE) {
        __hip_bfloat162 lo = __float22bfloat162_rn(make_float2(v.x, v.y));
        __hip_bfloat162 hi = __float22bfloat162_rn(make_float2(v.z, v.w));
        unsigned* d = (unsigned*)(tile + row * 258 + (j << 2));
        d[0] = *(unsigned*)&lo;
        d[1] = *(unsigned*)&hi;
      }
    }
#pragma unroll
    for (int o = 1; o < 16; o <<= 1) {
      sum += __shfl_xor(sum, o);
      mx = fmaxf(mx, __shfl_xor(mx, o));
    }
    if (lp == 0) {
      st_wt_f32(ws + OFF_PARTS + (((ssp << 6) + row) << 8) + chunk, sum);
      st_wt_f32(ws + OFF_PARTM + (((ssp << 6) + row) << 8) + chunk, mx);
    }
  }
}

// ---------------- persistent mega-kernel ----------------
// grid MUST be 1024 x 256. LDS ~36KB + launch_bounds(256,4) => 4 blocks/CU => co-resident.
__global__ __launch_bounds__(256, 4) void k_mega(
    const float* __restrict__ f1, const float* __restrict__ f2,
    float* __restrict__ ws, float* __restrict__ out,
    const float* __restrict__ w_avg1, const float* __restrict__ b_avg1,
    const float* __restrict__ w_max1, const float* __restrict__ b_max1,
    const float* __restrict__ w_avg11, const float* __restrict__ b_avg11,
    const float* __restrict__ w_max11, const float* __restrict__ b_max11,
    const float* __restrict__ w_avg2, const float* __restrict__ b_avg2,
    const float* __restrict__ w_max2, const float* __restrict__ b_max2,
    const float* __restrict__ w_avg22, const float* __restrict__ b_avg22,
    const float* __restrict__ w_max22, const float* __restrict__ b_max22,
    const float* __restrict__ cw1, const float* __restrict__ cb1,
    const float* __restrict__ cw2, const float* __restrict__ cb2) {

  __shared__ union {
    unsigned short tile[64 * 258];                               // 33024 B
    struct { float pl[2][20][36]; float t1l[18][34]; } cv;       // conv phase
    float yst[512];                                              // final phase
  } sm;
  __shared__ float red[8];
  // MLP/P scratch -- separate from tile (tile stays resident across P1)
  __shared__ float s_in[4][64];        // avg1, mx1, avg2, mx2
  __shared__ float s_h[4][32];         // ha1, hm1, ha2, hm2
  __shared__ float s_a1[64], s_a2[64], s_mm[4];
  __shared__ float s_rm[2][64], s_ri[2][64];   // per-row softmax max & 1/sum

  unsigned* fl = (unsigned*)ws;
  const int tid = threadIdx.x;
  const int bx  = blockIdx.x;
  const int lane = tid & 63, wv = tid >> 6;

  const int ss1 = bx >> 8, chunk = bx & 255, n0 = chunk << 8;
  const float* fb1 = f1 + ((size_t)ss1 << 22);   // slice ss1   (f1 batch ss1)
  const float* fb2 = f2 + ((size_t)ss1 << 22);   // slice ss1+4 (f2 batch ss1)

  // ======== P0: tile1 -> LDS bf16 + stats; tile2 stats-only ========
  p0_tile<true >(fb1, n0, ss1,     chunk, sm.tile, ws, lane, wv);
  p0_tile<false>(fb2, n0, ss1 + 4, chunk, sm.tile, ws, lane, wv);
  signal(fl + D0 + (bx << 2));

  // ======== P1a: stats reduction over 256 tiles (blocks 0..127, 4 rows each) ========
  if (bx < 128) {
    int ssx = bx >> 4;   // slice of my rows
    wait_slots(fl, D0 + ((((ssx & 3) << 8) | tid) << 2), true);
    int r = (bx << 2) + wv;                       // global row = ss*64+ch
    float4 s4 = *(const float4*)(ws + OFF_PARTS + (r << 8) + (lane << 2));
    float4 m4 = *(const float4*)(ws + OFF_PARTM + (r << 8) + (lane << 2));
    float s = (s4.x + s4.y) + (s4.z + s4.w);
    float m = fmaxf(fmaxf(m4.x, m4.y), fmaxf(m4.z, m4.w));
    for (int o = 32; o > 0; o >>= 1) {
      s += __shfl_xor(s, o);
      m = fmaxf(m, __shfl_xor(m, o));
    }
    if (lane == 0) {
      st_wt_f32(ws + OFF_AVG + r, s * (1.f / 65536.f));
      st_wt_f32(ws + OFF_MXA + r, m);
    }
    signal(fl + D1A + (bx << 2));
  }

  // ======== P1b (distributed): every block redundantly computes MLP + P stats ========
  {
    int fidx = (tid < 16) ? (ss1 * 16 + tid) : ((ss1 + 4) * 16 + (tid - 16));
    wait_slots(fl, D1A + (fidx << 2), tid < 32);
  }
  if (tid < 64) {
    s_in[0][tid] = ws[OFF_AVG + (ss1 << 6) + tid];
    s_in[1][tid] = ws[OFF_MXA + (ss1 << 6) + tid];
    s_in[2][tid] = ws[OFF_AVG + ((ss1 + 4) << 6) + tid];
    s_in[3][tid] = ws[OFF_MXA + ((ss1 + 4) << 6) + tid];
  }
  __syncthreads();
  if (tid < 128) {                    // layer 1: 4 x 32 hidden units
    int u = tid & 31, which = tid >> 5;
    const float* W = (which == 0) ? w_avg1 : (which == 1) ? w_max1
                   : (which == 2) ? w_avg2 : w_max2;
    const float* B = (which == 0) ? b_avg1 : (which == 1) ? b_max1
                   : (which == 2) ? b_avg2 : b_max2;
    float s = B[u];
    for (int c2 = 0; c2 < 64; ++c2) s += W[u * 64 + c2] * s_in[which][c2];
    s_h[which][u] = fmaxf(s, 0.f);
  }
  __syncthreads();
  if (tid < 128) {                    // layer 2: a1[64], a2[64]
    int u = tid & 63, which = tid >> 6;
    const float* Wa = which ? w_avg22 : w_avg11;
    const float* Wm = which ? w_max22 : w_max11;
    float s = which ? (b_avg22[u] + b_max22[u]) : (b_avg11[u] + b_max11[u]);
    const float* ha = s_h[which ? 2 : 0];
    const float* hm = s_h[which ? 3 : 1];
    for (int k = 0; k < 32; ++k) s += Wa[u * 32 + k] * ha[k] + Wm[u * 32 + k] * hm[k];
    (which ? s_a2 : s_a1)[u] = s;
  }
  __syncthreads();
  if (wv == 0) {                      // extrema of a2
    float v = s_a2[lane], mxv = v, mnv = v;
    for (int o = 32; o > 0; o >>= 1) {
      mxv = fmaxf(mxv, __shfl_xor(mxv, o));
      mnv = fminf(mnv, __shfl_xor(mnv, o));
    }
    if (lane == 0) { s_mm[0] = mxv; s_mm[1] = mnv; }
  } else if (wv == 1) {               // extrema of a1
    float v = s_a1[lane], mxv = v, mnv = v;
    for (int o = 32; o > 0; o >>= 1) {
      mxv = fmaxf(mxv, __shfl_xor(mxv, o));
      mnv = fminf(mnv, __shfl_xor(mnv, o));
    }
    if (lane == 0) { s_mm[2] = mxv; s_mm[3] = mnv; }
  }
  __syncthreads();
  {                                    // per-row softmax stats: 128 rows x 2 threads
    int r = tid >> 1, half = tid & 1;
    int sel = r >> 6, i = r & 63;
    float sv = sel ? s_a2[i] : s_a1[i];
    const float* col = sel ? s_a1 : s_a2;
    float mrow = (sv >= 0.f) ? sv * (sel ? s_mm[2] : s_mm[0])
                             : sv * (sel ? s_mm[3] : s_mm[1]);
    float sum = 0.f;
    int j0 = half << 5;
    for (int j = j0; j < j0 + 32; ++j) sum += __expf(sv * col[j] - mrow);
    sum += __shfl_xor(sum, 1);        // tid pairs (2r, 2r+1) share a wave
    if (half == 0) { s_rm[sel][i] = mrow; s_ri[sel][i] = 1.f / sum; }
  }
  __syncthreads();

  // ======== P2: at = P @ f via MFMA, channel mean/max -> packed pool ========
  {
    const int c = lane & 15, q = lane >> 4;
    const int pxb = wv << 6;

    auto build_A = [&](int sel, bf16x8 (&A)[4][2]) {
      const float* col = sel ? s_a1 : s_a2;
#pragma unroll
      for (int mt = 0; mt < 4; ++mt) {
        int i = mt * 16 + c;
        float sv = sel ? s_a2[i] : s_a1[i];
        float mrow = s_rm[sel][i], inv = s_ri[sel][i];
#pragma unroll
        for (int s = 0; s < 2; ++s) {
          union { bf16x8 v; __hip_bfloat162 h[4]; } u;
#pragma unroll
          for (int jj = 0; jj < 4; ++jj) {
            int j = s * 32 + q * 8 + jj * 2;
            float e0 = __expf(sv * col[j]     - mrow) * inv;
            float e1 = __expf(sv * col[j + 1] - mrow) * inv;
            u.h[jj] = __float22bfloat162_rn(make_float2(e0, e1));
          }
          A[mt][s] = u.v;
        }
      }
    };

    auto mfma_tile = [&](int ss, const bf16x8 (&A)[4][2]) {
      unsigned* poolu = (unsigned*)(ws + OFF_POOL) + (size_t)ss * HW;
#pragma unroll
      for (int nt = 0; nt < 4; ++nt) {
        int pcol = pxb + (nt << 4) + c;
        union { bf16x8 v; unsigned short s[8]; } u0, u1;
#pragma unroll
        for (int j = 0; j < 8; ++j) {
          u0.s[j] = sm.tile[(q * 8 + j) * 258 + pcol];
          u1.s[j] = sm.tile[(32 + q * 8 + j) * 258 + pcol];
        }
        f32x4 acc[4];
#pragma unroll
        for (int mt = 0; mt < 4; ++mt) {
          acc[mt] = (f32x4){0.f, 0.f, 0.f, 0.f};
          acc[mt] = __builtin_amdgcn_mfma_f32_16x16x32_bf16(A[mt][0], u0.v, acc[mt], 0, 0, 0);
          acc[mt] = __builtin_amdgcn_mfma_f32_16x16x32_bf16(A[mt][1], u1.v, acc[mt], 0, 0, 0);
        }
        float sum = 0.f, mxv = -3.4e38f;
#pragma unroll
        for (int mt = 0; mt < 4; ++mt)
#pragma unroll
          for (int r = 0; r < 4; ++r) {
            float v = acc[mt][r];
            sum += v;
            mxv = fmaxf(mxv, v);
          }
        sum += __shfl_xor(sum, 16);
        sum += __shfl_xor(sum, 32);
        mxv = fmaxf(mxv, __shfl_xor(mxv, 16));
        mxv = fmaxf(mxv, __shfl_xor(mxv, 32));
        // pack (mean, max) as bf16x2, one u32 store per pixel
        __hip_bfloat162 pk = __float22bfloat162_rn(make_float2(sum * (1.f / 64.f), mxv));
        if (q == 0) st_wt_u32(poolu + n0 + pcol, *(unsigned*)&pk);
      }
    };

    bf16x8 A[4][2];
    build_A(0, A);
    mfma_tile(ss1, A);                 // tile 1: resident since P0
    __syncthreads();
    stage_tile(fb2, n0, sm.tile, tid); // tile 2: f2 slice, L3-hot from P0
    __syncthreads();
    build_A(1, A);
    mfma_tile(ss1 + 4, A);
  }
  signal(fl + D2 + (bx << 2));

  // ======== P3: fused conv1(relu)+conv2 on 16x32 tiles + tile softmax stats ========
  {
    int ss = bx >> 7, tile_id = bx & 127;
    int h0 = (tile_id >> 3) << 4;
    int w0 = (tile_id & 7) << 5;
    {  // wait for the <=20 pool-row producers of this halo
      int rr = h0 - 2 + tid;
      bool act = (tid < 20) && (rr >= 0) && (rr < 256);
      wait_slots(fl, D2 + ((((ss & 3) << 8) + rr) << 2), act);
    }
    const unsigned* pp = (const unsigned*)(ws + OFF_POOL) + (size_t)ss * HW;
    float c1b = cb1[0], c2b = cb2[0];
    for (int i = tid; i < 720; i += 256) {        // 20 x 36 halo pool tile (packed)
      int rr = i / 36, cc = i - rr * 36;
      int h = h0 - 2 + rr, w = w0 - 2 + cc;
      unsigned pk = 0u;
      if (h >= 0 && h < 256 && w >= 0 && w < 256) pk = pp[(h << 8) + w];
      sm.cv.pl[0][rr][cc] = __uint_as_float(pk << 16);           // mean (bf16 lo)
      sm.cv.pl[1][rr][cc] = __uint_as_float(pk & 0xffff0000u);   // max  (bf16 hi)
    }
    __syncthreads();
    for (int i = tid; i < 612; i += 256) {        // 18 x 34 t1 tile
      int rr = i / 34, cc = i - rr * 34;
      int h = h0 - 1 + rr, w = w0 - 1 + cc;
      float s = c1b;
#pragma unroll
      for (int ci = 0; ci < 2; ++ci)
#pragma unroll
        for (int kh = 0; kh < 3; ++kh)
#pragma unroll
          for (int kw = 0; kw < 3; ++kw)
            s += sm.cv.pl[ci][rr + kh][cc + kw] * cw1[ci * 9 + kh * 3 + kw];
      bool in = (h >= 0 && h < 256 && w >= 0 && w < 256);
      sm.cv.t1l[rr][cc] = in ? fmaxf(s, 0.f) : 0.f;
    }
    __syncthreads();
    float myy[2];
    float m = -3.4e38f;
#pragma unroll
    for (int k2 = 0; k2 < 2; ++k2) {              // 16 x 32 y tile, 2 px/thread
      int i = tid + (k2 << 8);
      int rr = i >> 5, cc = i & 31;
      float s = c2b;
#pragma unroll
      for (int kh = 0; kh < 3; ++kh)
#pragma unroll
        for (int kw = 0; kw < 3; ++kw)
          s += sm.cv.t1l[rr + kh][cc + kw] * cw2[kh * 3 + kw];
      st_wt_f32(ws + OFF_Y + (ss << 16) + ((h0 + rr) << 8) + w0 + cc, s);
      myy[k2] = s;
      m = fmaxf(m, s);
    }
    for (int o = 32; o > 0; o >>= 1) m = fmaxf(m, __shfl_xor(m, o));
    if (lane == 0) red[wv] = m;
    __syncthreads();
    float Mb = fmaxf(fmaxf(red[0], red[1]), fmaxf(red[2], red[3]));
    float z = __expf(myy[0] - Mb) + __expf(myy[1] - Mb);
    for (int o = 32; o > 0; o >>= 1) z += __shfl_xor(z, o);
    if (lane == 0) red[4 + wv] = z;
    __syncthreads();
    if (tid == 0) {
      st_wt_f32(ws + OFF_BM + bx, Mb);
      st_wt_f32(ws + OFF_BS + bx, red[4] + red[5] + red[6] + red[7]);
    }
  }
  signal(fl + D3 + (bx << 2));

  // ======== P4: prefetch f | wait | per-slice combine | o = f * (1 + g) ========
  {
    int ss = bx >> 7, wq = bx & 127;
    int p0 = wq << 9;                       // this block's 512-px span
    const float* fsl = (ss >= 4) ? (f2 + ((size_t)(ss - 4) << 22))
                                 : (f1 + ((size_t)ss << 22));
    float* osl = out + ((size_t)ss << 22);
    int c0 = tid >> 7;
    int pxo = (tid & 127) << 2;
    // prefetch first 8 channel-rows of f (pure input, no dependency on flags)
    f32x4 pf[8];
#pragma unroll
    for (int i = 0; i < 8; ++i)
      pf[i] = *(const f32x4*)(fsl + (size_t)((i << 1) + c0) * HW + p0 + pxo);

    wait_slots(fl, D3 + ((ss * 128 + (tid & 127)) << 2), tid < 128);
    float m = (tid < 128) ? ws[OFF_BM + ss * 128 + tid] : -3.4e38f;
    for (int o = 32; o > 0; o >>= 1) m = fmaxf(m, __shfl_xor(m, o));
    if (lane == 0) red[wv] = m;
    __syncthreads();
    float M = fmaxf(fmaxf(red[0], red[1]), fmaxf(red[2], red[3]));
    float z = (tid < 128) ? __expf(ws[OFF_BM + ss * 128 + tid] - M) * ws[OFF_BS + ss * 128 + tid] : 0.f;
    for (int o = 32; o > 0; o >>= 1) z += __shfl_xor(z, o);
    if (lane == 0) red[4 + wv] = z;
    __syncthreads();
    float iZ = 1.f / (red[4] + red[5] + red[6] + red[7]);
    if (tid < 128) {
      float4 vy = *(const float4*)(ws + OFF_Y + (ss << 16) + p0 + (tid << 2));
      *(float4*)(&sm.yst[tid << 2]) = vy;
    }
    __syncthreads();
    float4 yv = *(const float4*)(&sm.yst[pxo]);
    f32x4 g;
    g.x = 1.f + __expf(yv.x - M) * iZ;
    g.y = 1.f + __expf(yv.y - M) * iZ;
    g.z = 1.f + __expf(yv.z - M) * iZ;
    g.w = 1.f + __expf(yv.w - M) * iZ;
#pragma unroll
    for (int i = 0; i < 8; ++i) {
      size_t gi = (size_t)((i << 1) + c0) * HW + p0 + pxo;
      f32x4 o = pf[i] * g;
      __builtin_nontemporal_store(o, (f32x4*)(osl + gi));
    }
#pragma unroll 8
    for (int i = 8; i < 32; ++i) {
      size_t gi = (size_t)((i << 1) + c0) * HW + p0 + pxo;
      f32x4 fv = *(const f32x4*)(fsl + gi);
      f32x4 o = fv * g;
      __builtin_nontemporal_store(o, (f32x4*)(osl + gi));
    }
  }
}

extern "C" void kernel_launch(void* const* d_in, const int* in_sizes, int n_in,
                              void* d_out, int out_size, void* d_ws, size_t ws_size,
                              hipStream_t stream) {
  const float* f1 = (const float*)d_in[0];
  const float* f2 = (const float*)d_in[1];
  const float* w_avg1  = (const float*)d_in[2];
  const float* b_avg1  = (const float*)d_in[3];
  const float* w_max1  = (const float*)d_in[4];
  const float* b_max1  = (const float*)d_in[5];
  const float* w_avg11 = (const float*)d_in[6];
  const float* b_avg11 = (const float*)d_in[7];
  const float* w_max11 = (const float*)d_in[8];
  const float* b_max11 = (const float*)d_in[9];
  const float* w_avg2  = (const float*)d_in[10];
  const float* b_avg2  = (const float*)d_in[11];
  const float* w_max2  = (const float*)d_in[12];
  const float* b_max2  = (const float*)d_in[13];
  const float* w_avg22 = (const float*)d_in[14];
  const float* b_avg22 = (const float*)d_in[15];
  const float* w_max22 = (const float*)d_in[16];
  const float* b_max22 = (const float*)d_in[17];
  const float* conv1_w = (const float*)d_in[18];
  const float* conv1_b = (const float*)d_in[19];
  const float* conv2_w = (const float*)d_in[20];
  const float* conv2_b = (const float*)d_in[21];
  float* ws = (float*)d_ws;
  float* out = (float*)d_out;

  // zero the flag arrays
  (void)hipMemsetAsync(d_ws, 0, FLAGS_BYTES, stream);
  k_mega<<<1024, 256, 0, stream>>>(f1, f2, ws, out,
                                   w_avg1, b_avg1, w_max1, b_max1,
                                   w_avg11, b_avg11, w_max11, b_max11,
                                   w_avg2, b_avg2, w_max2, b_max2,
                                   w_avg22, b_avg22, w_max22, b_max22,
                                   conv1_w, conv1_b, conv2_w, conv2_b);
}